// Round 1
// baseline (616.544 us; speedup 1.0000x reference)
//
#include <hip/hip_runtime.h>
#include <stdint.h>

#define N_NODES 100000
#define N_EDGES 3200000
#define NFEAT 512
#define NHID 256
#define MPAD 100096  // 782 * 128

typedef __attribute__((ext_vector_type(8))) short bf16x8_t;  // 8 bf16 in 4 VGPRs
typedef __attribute__((ext_vector_type(4))) float f32x4_t;

__device__ inline unsigned short f2bf(float f) {
  union { float f; uint32_t u; } x; x.f = f;
  uint32_t r = x.u + 0x7fffu + ((x.u >> 16) & 1u);  // RNE
  return (unsigned short)(r >> 16);
}
__device__ inline float b2f(unsigned short u) {
  union { uint32_t u; float f; } x; x.u = ((uint32_t)u) << 16;
  return x.f;
}

// ---- prep: W1 [512][256] -> W1T bf16 [256][512]; W2 [256][256] -> W2T bf16 [256][256]
__global__ void prep_k(const float* __restrict__ W1, const float* __restrict__ W2,
                       unsigned short* __restrict__ W1T, unsigned short* __restrict__ W2T) {
  int i = blockIdx.x * 256 + threadIdx.x;  // grid covers exactly 512*256 + 256*256
  if (i < NFEAT * NHID) {
    int k = i >> 8, n = i & 255;
    W1T[n * NFEAT + k] = f2bf(W1[i]);
  } else {
    int j = i - NFEAT * NHID;
    int k = j >> 8, n = j & 255;
    W2T[n * NHID + k] = f2bf(W2[j]);
  }
}

// ---- row_ptr[r] = lower_bound(edge_row, r), r in [0, N_NODES]
__global__ void rowptr_k(const int* __restrict__ erow, int* __restrict__ rowptr) {
  int r = blockIdx.x * 256 + threadIdx.x;
  if (r > N_NODES) return;
  int lo = 0, hi = N_EDGES;
  while (lo < hi) {
    int mid = (lo + hi) >> 1;
    if (erow[mid] < r) lo = mid + 1; else hi = mid;
  }
  rowptr[r] = lo;
}

// ---- GEMM C[M][256] (bf16 out) = A[M][K] @ BT[256][K]^T, 128x128 tile, BK=64
// A_FP32: A is fp32, reg-staged + converted to bf16 into swizzled LDS.
// else:   A is bf16, staged via global_load_lds with pre-swizzled source addr.
// LDS swizzle (T2): ushort index = row*64 + (cu ^ ((row&7)<<3))  [byte: ^((row&7)<<4)]
template <bool A_FP32>
__global__ __launch_bounds__(256) void gemm_bt(const void* __restrict__ Ap,
                                               const unsigned short* __restrict__ BT,
                                               unsigned short* __restrict__ C,
                                               int K, int Mreal) {
  __shared__ __align__(16) unsigned short As[128 * 64];
  __shared__ __align__(16) unsigned short Bs[128 * 64];
  const int tid = threadIdx.x;
  const int lane = tid & 63, wid = tid >> 6;
  const int wm = wid >> 1, wn = wid & 1;
  const int m0 = blockIdx.x * 128, n0 = blockIdx.y * 128;
  const int lrow = lane & 15, lhi = lane >> 4;

  f32x4_t acc[4][4] = {};

  const int nt = K >> 6;
  for (int t = 0; t < nt; ++t) {
    __syncthreads();  // WAR: previous compute done before restage
    if constexpr (A_FP32) {
      const float* A = (const float*)Ap;
      const int rr = tid >> 4;
      const int kq = (tid & 15) << 2;  // bf16-element quad offset in row
#pragma unroll
      for (int round = 0; round < 8; ++round) {
        int row = rr + (round << 4);
        int grow = m0 + row; grow = grow < Mreal ? grow : Mreal - 1;  // clamp tail
        const float4 v = *(const float4*)((const float*)A + (size_t)grow * K + (t << 6) + kq);
        ushort4 b4;
        b4.x = f2bf(v.x); b4.y = f2bf(v.y); b4.z = f2bf(v.z); b4.w = f2bf(v.w);
        *(ushort4*)&As[(row << 6) + (kq ^ ((row & 7) << 3))] = b4;
      }
    } else {
      const unsigned short* A = (const unsigned short*)Ap;
      const int Lrow = tid >> 3;
      const int Lc = (tid & 7) << 4;  // byte offset within 128B tile row
#pragma unroll
      for (int round = 0; round < 4; ++round) {
        int row = Lrow + (round << 5);
        int srcc = Lc ^ ((row & 7) << 4);  // pre-swizzled global source
        const char* g = (const char*)(A + (size_t)(m0 + row) * K + (t << 6)) + srcc;
        __builtin_amdgcn_global_load_lds(
            (const __attribute__((address_space(1))) void*)g,
            (__attribute__((address_space(3))) void*)((char*)As + (wid << 10) + (round << 12)),
            16, 0, 0);
      }
    }
    {
      const int Lrow = tid >> 3;
      const int Lc = (tid & 7) << 4;
#pragma unroll
      for (int round = 0; round < 4; ++round) {
        int row = Lrow + (round << 5);
        int srcc = Lc ^ ((row & 7) << 4);
        const char* g = (const char*)(BT + (size_t)(n0 + row) * K + (t << 6)) + srcc;
        __builtin_amdgcn_global_load_lds(
            (const __attribute__((address_space(1))) void*)g,
            (__attribute__((address_space(3))) void*)((char*)Bs + (wid << 10) + (round << 12)),
            16, 0, 0);
      }
    }
    asm volatile("s_waitcnt vmcnt(0)" ::: "memory");
    __syncthreads();  // RAW: tile staged

#pragma unroll
    for (int ks = 0; ks < 2; ++ks) {
      bf16x8_t af[4], bfr[4];
      const int cu = (ks << 5) + (lhi << 3);
#pragma unroll
      for (int mf = 0; mf < 4; ++mf) {
        int row = (wm << 6) + (mf << 4) + lrow;
        af[mf] = *(const bf16x8_t*)&As[(row << 6) + (cu ^ ((row & 7) << 3))];
      }
#pragma unroll
      for (int nf = 0; nf < 4; ++nf) {
        int row = (wn << 6) + (nf << 4) + lrow;
        bfr[nf] = *(const bf16x8_t*)&Bs[(row << 6) + (cu ^ ((row & 7) << 3))];
      }
#pragma unroll
      for (int mf = 0; mf < 4; ++mf)
#pragma unroll
        for (int nf = 0; nf < 4; ++nf)
          acc[mf][nf] = __builtin_amdgcn_mfma_f32_16x16x32_bf16(af[mf], bfr[nf], acc[mf][nf], 0, 0, 0);
    }
  }

  // epilogue: C/D layout col=lane&15, row=(lane>>4)*4+j  [m89-verified]
#pragma unroll
  for (int mf = 0; mf < 4; ++mf)
#pragma unroll
    for (int nf = 0; nf < 4; ++nf)
#pragma unroll
      for (int j = 0; j < 4; ++j) {
        int gm = m0 + (wm << 6) + (mf << 4) + (lhi << 2) + j;
        int gn = n0 + (wn << 6) + (nf << 4) + lrow;
        C[(size_t)gm * 256 + gn] = f2bf(acc[mf][nf][j]);
      }
}

// ---- SpMM1 + bias + relu + dropout -> H (bf16). One wave per row, lane owns 4 cols.
__global__ __launch_bounds__(256) void spmm1_k(const unsigned short* __restrict__ XW1,
                                               const int* __restrict__ rowptr,
                                               const int* __restrict__ ecol,
                                               const float* __restrict__ ew,
                                               const float* __restrict__ b1,
                                               const float* __restrict__ du,
                                               unsigned short* __restrict__ H) {
  const int lane = threadIdx.x & 63, wid = threadIdx.x >> 6;
  const int r = blockIdx.x * 4 + wid;
  const int c4 = lane << 2;
  if (r >= N_NODES) {  // pad rows: zero so GEMM2 reads clean zeros
    ushort4 z; z.x = z.y = z.z = z.w = 0;
    *(ushort4*)&H[(size_t)r * 256 + c4] = z;
    return;
  }
  float a0 = 0, a1 = 0, a2 = 0, a3 = 0;
  const int e1 = rowptr[r + 1];
  int e = rowptr[r];
  for (; e + 1 < e1; e += 2) {  // 2-deep gather pipeline
    int ca = ecol[e], cb = ecol[e + 1];
    float wa = ew[e], wb = ew[e + 1];
    ushort4 va = *(const ushort4*)&XW1[(size_t)ca * 256 + c4];
    ushort4 vb = *(const ushort4*)&XW1[(size_t)cb * 256 + c4];
    a0 += wa * b2f(va.x) + wb * b2f(vb.x);
    a1 += wa * b2f(va.y) + wb * b2f(vb.y);
    a2 += wa * b2f(va.z) + wb * b2f(vb.z);
    a3 += wa * b2f(va.w) + wb * b2f(vb.w);
  }
  if (e < e1) {
    int c = ecol[e]; float w = ew[e];
    ushort4 v = *(const ushort4*)&XW1[(size_t)c * 256 + c4];
    a0 += w * b2f(v.x); a1 += w * b2f(v.y); a2 += w * b2f(v.z); a3 += w * b2f(v.w);
  }
  const float4 bb = *(const float4*)&b1[c4];
  const float4 u = *(const float4*)&du[(size_t)r * 256 + c4];
  float h0 = fmaxf(a0 + bb.x, 0.f) * (u.x < 0.5f ? 2.f : 0.f);
  float h1 = fmaxf(a1 + bb.y, 0.f) * (u.y < 0.5f ? 2.f : 0.f);
  float h2 = fmaxf(a2 + bb.z, 0.f) * (u.z < 0.5f ? 2.f : 0.f);
  float h3 = fmaxf(a3 + bb.w, 0.f) * (u.w < 0.5f ? 2.f : 0.f);
  ushort4 o; o.x = f2bf(h0); o.y = f2bf(h1); o.z = f2bf(h2); o.w = f2bf(h3);
  *(ushort4*)&H[(size_t)r * 256 + c4] = o;
}

// ---- SpMM2 + bias + relu + log_softmax -> out (fp32)
__global__ __launch_bounds__(256) void spmm2_k(const unsigned short* __restrict__ HW2,
                                               const int* __restrict__ rowptr,
                                               const int* __restrict__ ecol,
                                               const float* __restrict__ ew,
                                               const float* __restrict__ b2,
                                               float* __restrict__ out) {
  const int lane = threadIdx.x & 63, wid = threadIdx.x >> 6;
  const int r = blockIdx.x * 4 + wid;
  if (r >= N_NODES) return;
  const int c4 = lane << 2;
  float a0 = 0, a1 = 0, a2 = 0, a3 = 0;
  const int e1 = rowptr[r + 1];
  int e = rowptr[r];
  for (; e + 1 < e1; e += 2) {
    int ca = ecol[e], cb = ecol[e + 1];
    float wa = ew[e], wb = ew[e + 1];
    ushort4 va = *(const ushort4*)&HW2[(size_t)ca * 256 + c4];
    ushort4 vb = *(const ushort4*)&HW2[(size_t)cb * 256 + c4];
    a0 += wa * b2f(va.x) + wb * b2f(vb.x);
    a1 += wa * b2f(va.y) + wb * b2f(vb.y);
    a2 += wa * b2f(va.z) + wb * b2f(vb.z);
    a3 += wa * b2f(va.w) + wb * b2f(vb.w);
  }
  if (e < e1) {
    int c = ecol[e]; float w = ew[e];
    ushort4 v = *(const ushort4*)&HW2[(size_t)c * 256 + c4];
    a0 += w * b2f(v.x); a1 += w * b2f(v.y); a2 += w * b2f(v.z); a3 += w * b2f(v.w);
  }
  const float4 bb = *(const float4*)&b2[c4];
  float v0 = fmaxf(a0 + bb.x, 0.f);
  float v1 = fmaxf(a1 + bb.y, 0.f);
  float v2 = fmaxf(a2 + bb.z, 0.f);
  float v3 = fmaxf(a3 + bb.w, 0.f);
  float m = fmaxf(fmaxf(v0, v1), fmaxf(v2, v3));
#pragma unroll
  for (int off = 32; off > 0; off >>= 1) m = fmaxf(m, __shfl_xor(m, off));
  float s = expf(v0 - m) + expf(v1 - m) + expf(v2 - m) + expf(v3 - m);
#pragma unroll
  for (int off = 32; off > 0; off >>= 1) s += __shfl_xor(s, off);
  float ls = m + logf(s);
  float4 o; o.x = v0 - ls; o.y = v1 - ls; o.z = v2 - ls; o.w = v3 - ls;
  *(float4*)&out[(size_t)r * 256 + c4] = o;
}

extern "C" void kernel_launch(void* const* d_in, const int* in_sizes, int n_in,
                              void* d_out, int out_size, void* d_ws, size_t ws_size,
                              hipStream_t stream) {
  const float* x  = (const float*)d_in[0];
  const float* W1 = (const float*)d_in[1];
  const float* b1 = (const float*)d_in[2];
  const float* W2 = (const float*)d_in[3];
  const float* b2 = (const float*)d_in[4];
  const int* erow = (const int*)d_in[5];
  const int* ecol = (const int*)d_in[6];
  const float* ew = (const float*)d_in[7];
  const float* du = (const float*)d_in[8];
  float* out = (float*)d_out;

  char* ws = (char*)d_ws;
  unsigned short* W1T = (unsigned short*)ws;                    // 262144 B
  unsigned short* W2T = (unsigned short*)(ws + 262144);         // 131072 B
  int* rowptr = (int*)(ws + 262144 + 131072);                   // 400004 B (pad to 401408)
  unsigned short* XW1 = (unsigned short*)(ws + 262144 + 131072 + 401408);  // 51249152 B (reused as HW2)
  unsigned short* H = (unsigned short*)(ws + 262144 + 131072 + 401408 + 51249152);  // 51249152 B

  prep_k<<<768, 256, 0, stream>>>(W1, W2, W1T, W2T);
  rowptr_k<<<392, 256, 0, stream>>>(erow, rowptr);
  gemm_bt<true><<<dim3(782, 2), 256, 0, stream>>>((const void*)x, W1T, XW1, NFEAT, N_NODES);
  spmm1_k<<<MPAD / 4, 256, 0, stream>>>(XW1, rowptr, ecol, ew, b1, du, H);
  gemm_bt<false><<<dim3(782, 2), 256, 0, stream>>>((const void*)H, W2T, XW1, NHID, MPAD);
  spmm2_k<<<N_NODES / 4, 256, 0, stream>>>(XW1, rowptr, ecol, ew, b2, out);
}

// Round 2
// 566.111 us; speedup vs baseline: 1.0891x; 1.0891x over previous
//
#include <hip/hip_runtime.h>
#include <stdint.h>

#define N_NODES 100000
#define N_EDGES 3200000
#define NFEAT 512
#define NHID 256
#define MPAD 100096  // 782 * 128

typedef __attribute__((ext_vector_type(8))) short bf16x8_t;  // 8 bf16 in 4 VGPRs
typedef __attribute__((ext_vector_type(4))) float f32x4_t;

#define RFL(x) __builtin_amdgcn_readfirstlane(x)

__device__ inline unsigned short f2bf(float f) {
  union { float f; uint32_t u; } x; x.f = f;
  uint32_t r = x.u + 0x7fffu + ((x.u >> 16) & 1u);  // RNE
  return (unsigned short)(r >> 16);
}
__device__ inline float b2f(unsigned short u) {
  union { uint32_t u; float f; } x; x.u = ((uint32_t)u) << 16;
  return x.f;
}

// ---- prep: W1 [512][256] -> W1T bf16 [256][512]; W2 [256][256] -> W2T bf16 [256][256]
__global__ void prep_k(const float* __restrict__ W1, const float* __restrict__ W2,
                       unsigned short* __restrict__ W1T, unsigned short* __restrict__ W2T) {
  int i = blockIdx.x * 256 + threadIdx.x;  // grid covers exactly 512*256 + 256*256
  if (i < NFEAT * NHID) {
    int k = i >> 8, n = i & 255;
    W1T[n * NFEAT + k] = f2bf(W1[i]);
  } else {
    int j = i - NFEAT * NHID;
    int k = j >> 8, n = j & 255;
    W2T[n * NHID + k] = f2bf(W2[j]);
  }
}

// ---- row_ptr[r] = lower_bound(edge_row, r), r in [0, N_NODES]
__global__ void rowptr_k(const int* __restrict__ erow, int* __restrict__ rowptr) {
  int r = blockIdx.x * 256 + threadIdx.x;
  if (r > N_NODES) return;
  int lo = 0, hi = N_EDGES;
  while (lo < hi) {
    int mid = (lo + hi) >> 1;
    if (erow[mid] < r) lo = mid + 1; else hi = mid;
  }
  rowptr[r] = lo;
}

// ---- GEMM C[M][256] (bf16 out) = A[M][K] @ BT[256][K]^T
// BM=128, BN=256, BK=64, 512 threads (8 waves, 2x4), LDS 48KB, XOR-swizzled.
// A_FP32: A fp32, reg-staged + converted. else: A bf16 via global_load_lds.
template <bool A_FP32>
__global__ __launch_bounds__(512) void gemm_bt2(const void* __restrict__ Ap,
                                                const unsigned short* __restrict__ BT,
                                                unsigned short* __restrict__ C,
                                                int K, int Mreal) {
  __shared__ __align__(16) unsigned short As[128 * 64];  // 16 KB
  __shared__ __align__(16) unsigned short Bs[256 * 64];  // 32 KB
  const int tid = threadIdx.x;
  const int lane = tid & 63, wid = tid >> 6;
  const int wm = wid >> 2, wn = wid & 3;  // 2 x 4 waves, each 64x64 out
  const int m0 = blockIdx.x * 128;
  const int lrow = lane & 15, lhi = lane >> 4;

  f32x4_t acc[4][4] = {};

  const int nt = K >> 6;
  for (int t = 0; t < nt; ++t) {
    __syncthreads();  // WAR: previous compute done before restage
    if constexpr (A_FP32) {
      const float* A = (const float*)Ap;
      const int rr = tid >> 4;             // 0..31
      const int kq = (tid & 15) << 2;      // bf16-quad offset in row
#pragma unroll
      for (int round = 0; round < 4; ++round) {
        int row = rr + (round << 5);
        int grow = m0 + row; grow = grow < Mreal ? grow : Mreal - 1;  // clamp tail
        const float4 v = *(const float4*)(A + (size_t)grow * K + (t << 6) + kq);
        ushort4 b4;
        b4.x = f2bf(v.x); b4.y = f2bf(v.y); b4.z = f2bf(v.z); b4.w = f2bf(v.w);
        *(ushort4*)&As[(row << 6) + (kq ^ ((row & 7) << 3))] = b4;
      }
    } else {
      const unsigned short* A = (const unsigned short*)Ap;
      const int Lrow = tid >> 3;           // 0..63
      const int Lc = (tid & 7) << 4;       // byte offset in 128B row
#pragma unroll
      for (int round = 0; round < 2; ++round) {
        int row = Lrow + (round << 6);
        int srcc = Lc ^ ((row & 7) << 4);  // pre-swizzled global source
        const char* g = (const char*)(A + (size_t)(m0 + row) * K + (t << 6)) + srcc;
        __builtin_amdgcn_global_load_lds(
            (const __attribute__((address_space(1))) void*)g,
            (__attribute__((address_space(3))) void*)((char*)As + tid * 16 + (round << 13)),
            16, 0, 0);
      }
    }
    {
      const int Lrow = tid >> 3;
      const int Lc = (tid & 7) << 4;
#pragma unroll
      for (int round = 0; round < 4; ++round) {
        int row = Lrow + (round << 6);
        int srcc = Lc ^ ((row & 7) << 4);
        const char* g = (const char*)(BT + (size_t)row * K + (t << 6)) + srcc;
        __builtin_amdgcn_global_load_lds(
            (const __attribute__((address_space(1))) void*)g,
            (__attribute__((address_space(3))) void*)((char*)Bs + tid * 16 + (round << 13)),
            16, 0, 0);
      }
    }
    asm volatile("s_waitcnt vmcnt(0)" ::: "memory");
    __syncthreads();  // RAW: tile staged

#pragma unroll
    for (int ks = 0; ks < 2; ++ks) {
      bf16x8_t af[4], bfr[4];
      const int cu = (ks << 5) + (lhi << 3);
#pragma unroll
      for (int mf = 0; mf < 4; ++mf) {
        int row = (wm << 6) + (mf << 4) + lrow;
        af[mf] = *(const bf16x8_t*)&As[(row << 6) + (cu ^ ((row & 7) << 3))];
      }
#pragma unroll
      for (int nf = 0; nf < 4; ++nf) {
        int row = (wn << 6) + (nf << 4) + lrow;
        bfr[nf] = *(const bf16x8_t*)&Bs[(row << 6) + (cu ^ ((row & 7) << 3))];
      }
#pragma unroll
      for (int mf = 0; mf < 4; ++mf)
#pragma unroll
        for (int nf = 0; nf < 4; ++nf)
          acc[mf][nf] = __builtin_amdgcn_mfma_f32_16x16x32_bf16(af[mf], bfr[nf], acc[mf][nf], 0, 0, 0);
    }
  }

  // epilogue: C/D layout col=lane&15, row=(lane>>4)*4+j  [m89-verified]
#pragma unroll
  for (int mf = 0; mf < 4; ++mf)
#pragma unroll
    for (int nf = 0; nf < 4; ++nf)
#pragma unroll
      for (int j = 0; j < 4; ++j) {
        int gm = m0 + (wm << 6) + (mf << 4) + (lhi << 2) + j;
        int gn = (wn << 6) + (nf << 4) + lrow;
        C[(size_t)gm * 256 + gn] = f2bf(acc[mf][nf][j]);
      }
}

// ---- SpMM1 + bias + relu + dropout -> H (bf16). One wave per row, lane owns 4 cols.
// Edge stream scalarized (readfirstlane -> s_load), gathers 8-deep.
__global__ __launch_bounds__(256) void spmm1_k(const unsigned short* __restrict__ XW1,
                                               const int* __restrict__ rowptr,
                                               const int* __restrict__ ecol,
                                               const float* __restrict__ ew,
                                               const float* __restrict__ b1,
                                               const float* __restrict__ du,
                                               unsigned short* __restrict__ H) {
  const int lane = threadIdx.x & 63, wid = threadIdx.x >> 6;
  const int r = blockIdx.x * 4 + wid;
  const uint32_t c8 = (uint32_t)lane << 3;  // lane's byte offset (4 bf16)
  const int c4 = lane << 2;
  if (r >= N_NODES) {  // pad rows: zero so GEMM2 reads clean zeros
    ushort4 z; z.x = z.y = z.z = z.w = 0;
    *(ushort4*)&H[(size_t)r * 256 + c4] = z;
    return;
  }
  const char* Xb = (const char*)XW1;
  const float4 bb = *(const float4*)&b1[c4];
  const float4 u = *(const float4*)&du[(size_t)r * 256 + c4];
  float a0 = 0, a1 = 0, a2 = 0, a3 = 0;
  int e  = RFL(rowptr[r]);
  int e1 = RFL(rowptr[r + 1]);
  for (; e + 8 <= e1; e += 8) {  // 8-deep gather pipeline
    ushort4 v[8]; float w[8];
#pragma unroll
    for (int q = 0; q < 8; ++q) {
      uint32_t c = (uint32_t)RFL(ecol[e + q]);
      w[q] = __uint_as_float(RFL(__float_as_uint(ew[e + q])));
      v[q] = *(const ushort4*)(Xb + ((c << 9) + c8));
    }
#pragma unroll
    for (int q = 0; q < 8; ++q) {
      a0 += w[q] * b2f(v[q].x); a1 += w[q] * b2f(v[q].y);
      a2 += w[q] * b2f(v[q].z); a3 += w[q] * b2f(v[q].w);
    }
  }
  for (; e < e1; ++e) {
    uint32_t c = (uint32_t)RFL(ecol[e]);
    float w = __uint_as_float(RFL(__float_as_uint(ew[e])));
    ushort4 v = *(const ushort4*)(Xb + ((c << 9) + c8));
    a0 += w * b2f(v.x); a1 += w * b2f(v.y); a2 += w * b2f(v.z); a3 += w * b2f(v.w);
  }
  float h0 = fmaxf(a0 + bb.x, 0.f) * (u.x < 0.5f ? 2.f : 0.f);
  float h1 = fmaxf(a1 + bb.y, 0.f) * (u.y < 0.5f ? 2.f : 0.f);
  float h2 = fmaxf(a2 + bb.z, 0.f) * (u.z < 0.5f ? 2.f : 0.f);
  float h3 = fmaxf(a3 + bb.w, 0.f) * (u.w < 0.5f ? 2.f : 0.f);
  ushort4 o; o.x = f2bf(h0); o.y = f2bf(h1); o.z = f2bf(h2); o.w = f2bf(h3);
  *(ushort4*)&H[(size_t)r * 256 + c4] = o;
}

// ---- SpMM2 + bias + relu + log_softmax -> out (fp32)
__global__ __launch_bounds__(256) void spmm2_k(const unsigned short* __restrict__ HW2,
                                               const int* __restrict__ rowptr,
                                               const int* __restrict__ ecol,
                                               const float* __restrict__ ew,
                                               const float* __restrict__ b2,
                                               float* __restrict__ out) {
  const int lane = threadIdx.x & 63, wid = threadIdx.x >> 6;
  const int r = blockIdx.x * 4 + wid;
  if (r >= N_NODES) return;
  const uint32_t c8 = (uint32_t)lane << 3;
  const int c4 = lane << 2;
  const char* Xb = (const char*)HW2;
  const float4 bb = *(const float4*)&b2[c4];
  float a0 = 0, a1 = 0, a2 = 0, a3 = 0;
  int e  = RFL(rowptr[r]);
  int e1 = RFL(rowptr[r + 1]);
  for (; e + 8 <= e1; e += 8) {
    ushort4 v[8]; float w[8];
#pragma unroll
    for (int q = 0; q < 8; ++q) {
      uint32_t c = (uint32_t)RFL(ecol[e + q]);
      w[q] = __uint_as_float(RFL(__float_as_uint(ew[e + q])));
      v[q] = *(const ushort4*)(Xb + ((c << 9) + c8));
    }
#pragma unroll
    for (int q = 0; q < 8; ++q) {
      a0 += w[q] * b2f(v[q].x); a1 += w[q] * b2f(v[q].y);
      a2 += w[q] * b2f(v[q].z); a3 += w[q] * b2f(v[q].w);
    }
  }
  for (; e < e1; ++e) {
    uint32_t c = (uint32_t)RFL(ecol[e]);
    float w = __uint_as_float(RFL(__float_as_uint(ew[e])));
    ushort4 v = *(const ushort4*)(Xb + ((c << 9) + c8));
    a0 += w * b2f(v.x); a1 += w * b2f(v.y); a2 += w * b2f(v.z); a3 += w * b2f(v.w);
  }
  float v0 = fmaxf(a0 + bb.x, 0.f);
  float v1 = fmaxf(a1 + bb.y, 0.f);
  float v2 = fmaxf(a2 + bb.z, 0.f);
  float v3 = fmaxf(a3 + bb.w, 0.f);
  float m = fmaxf(fmaxf(v0, v1), fmaxf(v2, v3));
#pragma unroll
  for (int off = 32; off > 0; off >>= 1) m = fmaxf(m, __shfl_xor(m, off));
  float s = expf(v0 - m) + expf(v1 - m) + expf(v2 - m) + expf(v3 - m);
#pragma unroll
  for (int off = 32; off > 0; off >>= 1) s += __shfl_xor(s, off);
  float ls = m + logf(s);
  float4 o; o.x = v0 - ls; o.y = v1 - ls; o.z = v2 - ls; o.w = v3 - ls;
  *(float4*)&out[(size_t)r * 256 + c4] = o;
}

extern "C" void kernel_launch(void* const* d_in, const int* in_sizes, int n_in,
                              void* d_out, int out_size, void* d_ws, size_t ws_size,
                              hipStream_t stream) {
  const float* x  = (const float*)d_in[0];
  const float* W1 = (const float*)d_in[1];
  const float* b1 = (const float*)d_in[2];
  const float* W2 = (const float*)d_in[3];
  const float* b2 = (const float*)d_in[4];
  const int* erow = (const int*)d_in[5];
  const int* ecol = (const int*)d_in[6];
  const float* ew = (const float*)d_in[7];
  const float* du = (const float*)d_in[8];
  float* out = (float*)d_out;

  char* ws = (char*)d_ws;
  unsigned short* W1T = (unsigned short*)ws;                    // 262144 B
  unsigned short* W2T = (unsigned short*)(ws + 262144);         // 131072 B
  int* rowptr = (int*)(ws + 262144 + 131072);                   // 400004 B (pad to 401408)
  unsigned short* XW1 = (unsigned short*)(ws + 262144 + 131072 + 401408);  // 51249152 B (reused as HW2)
  unsigned short* H = (unsigned short*)(ws + 262144 + 131072 + 401408 + 51249152);  // 51249152 B

  prep_k<<<768, 256, 0, stream>>>(W1, W2, W1T, W2T);
  rowptr_k<<<392, 256, 0, stream>>>(erow, rowptr);
  gemm_bt2<true><<<782, 512, 0, stream>>>((const void*)x, W1T, XW1, NFEAT, N_NODES);
  spmm1_k<<<MPAD / 4, 256, 0, stream>>>(XW1, rowptr, ecol, ew, b1, du, H);
  gemm_bt2<false><<<782, 512, 0, stream>>>((const void*)H, W2T, XW1, NHID, MPAD);
  spmm2_k<<<N_NODES / 4, 256, 0, stream>>>(XW1, rowptr, ecol, ew, b2, out);
}

// Round 3
// 550.106 us; speedup vs baseline: 1.1208x; 1.0291x over previous
//
#include <hip/hip_runtime.h>
#include <stdint.h>

#define N_NODES 100000
#define N_EDGES 3200000
#define NFEAT 512
#define NHID 256
#define MPAD 100096  // 782 * 128

typedef __attribute__((ext_vector_type(8))) short bf16x8_t;  // 8 bf16 in 4 VGPRs
typedef __attribute__((ext_vector_type(4))) float f32x4_t;

#define RFL(x) __builtin_amdgcn_readfirstlane(x)

__device__ inline unsigned short f2bf(float f) {
  union { float f; uint32_t u; } x; x.f = f;
  uint32_t r = x.u + 0x7fffu + ((x.u >> 16) & 1u);  // RNE
  return (unsigned short)(r >> 16);
}
__device__ inline float b2f(unsigned short u) {
  union { uint32_t u; float f; } x; x.u = ((uint32_t)u) << 16;
  return x.f;
}

// ---- prep: W1 [512][256] -> W1T bf16 [256][512]; W2 [256][256] -> W2T bf16 [256][256]
__global__ void prep_k(const float* __restrict__ W1, const float* __restrict__ W2,
                       unsigned short* __restrict__ W1T, unsigned short* __restrict__ W2T) {
  int i = blockIdx.x * 256 + threadIdx.x;  // grid covers exactly 512*256 + 256*256
  if (i < NFEAT * NHID) {
    int k = i >> 8, n = i & 255;
    W1T[n * NFEAT + k] = f2bf(W1[i]);
  } else {
    int j = i - NFEAT * NHID;
    int k = j >> 8, n = j & 255;
    W2T[n * NHID + k] = f2bf(W2[j]);
  }
}

// ---- row_ptr[r] = lower_bound(edge_row, r), r in [0, N_NODES]
__global__ void rowptr_k(const int* __restrict__ erow, int* __restrict__ rowptr) {
  int r = blockIdx.x * 256 + threadIdx.x;
  if (r > N_NODES) return;
  int lo = 0, hi = N_EDGES;
  while (lo < hi) {
    int mid = (lo + hi) >> 1;
    if (erow[mid] < r) lo = mid + 1; else hi = mid;
  }
  rowptr[r] = lo;
}

// ---- GEMM C[M][256] (bf16 out) = A[M][K] @ BT[256][K]^T
// BM=128, BN=256, BK=64, 512 threads (8 waves, 2x4), LDS 48KB, XOR-swizzled.
template <bool A_FP32>
__global__ __launch_bounds__(512) void gemm_bt2(const void* __restrict__ Ap,
                                                const unsigned short* __restrict__ BT,
                                                unsigned short* __restrict__ C,
                                                int K, int Mreal) {
  __shared__ __align__(16) unsigned short As[128 * 64];  // 16 KB
  __shared__ __align__(16) unsigned short Bs[256 * 64];  // 32 KB
  const int tid = threadIdx.x;
  const int lane = tid & 63, wid = tid >> 6;
  const int wm = wid >> 2, wn = wid & 3;  // 2 x 4 waves, each 64x64 out
  const int m0 = blockIdx.x * 128;
  const int lrow = lane & 15, lhi = lane >> 4;

  f32x4_t acc[4][4] = {};

  const int nt = K >> 6;
  for (int t = 0; t < nt; ++t) {
    __syncthreads();  // WAR: previous compute done before restage
    if constexpr (A_FP32) {
      const float* A = (const float*)Ap;
      const int rr = tid >> 4;             // 0..31
      const int kq = (tid & 15) << 2;      // bf16-quad offset in row
#pragma unroll
      for (int round = 0; round < 4; ++round) {
        int row = rr + (round << 5);
        int grow = m0 + row; grow = grow < Mreal ? grow : Mreal - 1;  // clamp tail
        const f32x4_t v = __builtin_nontemporal_load(
            (const f32x4_t*)(A + (size_t)grow * K + (t << 6) + kq));  // x streamed once
        ushort4 b4;
        b4.x = f2bf(v.x); b4.y = f2bf(v.y); b4.z = f2bf(v.z); b4.w = f2bf(v.w);
        *(ushort4*)&As[(row << 6) + (kq ^ ((row & 7) << 3))] = b4;
      }
    } else {
      const unsigned short* A = (const unsigned short*)Ap;
      const int Lrow = tid >> 3;           // 0..63
      const int Lc = (tid & 7) << 4;       // byte offset in 128B row
#pragma unroll
      for (int round = 0; round < 2; ++round) {
        int row = Lrow + (round << 6);
        int srcc = Lc ^ ((row & 7) << 4);  // pre-swizzled global source
        const char* g = (const char*)(A + (size_t)(m0 + row) * K + (t << 6)) + srcc;
        __builtin_amdgcn_global_load_lds(
            (const __attribute__((address_space(1))) void*)g,
            (__attribute__((address_space(3))) void*)((char*)As + tid * 16 + (round << 13)),
            16, 0, 0);
      }
    }
    {
      const int Lrow = tid >> 3;
      const int Lc = (tid & 7) << 4;
#pragma unroll
      for (int round = 0; round < 4; ++round) {
        int row = Lrow + (round << 6);
        int srcc = Lc ^ ((row & 7) << 4);
        const char* g = (const char*)(BT + (size_t)row * K + (t << 6)) + srcc;
        __builtin_amdgcn_global_load_lds(
            (const __attribute__((address_space(1))) void*)g,
            (__attribute__((address_space(3))) void*)((char*)Bs + tid * 16 + (round << 13)),
            16, 0, 0);
      }
    }
    asm volatile("s_waitcnt vmcnt(0)" ::: "memory");
    __syncthreads();  // RAW: tile staged

#pragma unroll
    for (int ks = 0; ks < 2; ++ks) {
      bf16x8_t af[4], bfr[4];
      const int cu = (ks << 5) + (lhi << 3);
#pragma unroll
      for (int mf = 0; mf < 4; ++mf) {
        int row = (wm << 6) + (mf << 4) + lrow;
        af[mf] = *(const bf16x8_t*)&As[(row << 6) + (cu ^ ((row & 7) << 3))];
      }
#pragma unroll
      for (int nf = 0; nf < 4; ++nf) {
        int row = (wn << 6) + (nf << 4) + lrow;
        bfr[nf] = *(const bf16x8_t*)&Bs[(row << 6) + (cu ^ ((row & 7) << 3))];
      }
#pragma unroll
      for (int mf = 0; mf < 4; ++mf)
#pragma unroll
        for (int nf = 0; nf < 4; ++nf)
          acc[mf][nf] = __builtin_amdgcn_mfma_f32_16x16x32_bf16(af[mf], bfr[nf], acc[mf][nf], 0, 0, 0);
    }
  }

  // epilogue: C/D layout col=lane&15, row=(lane>>4)*4+j  [m89-verified]
#pragma unroll
  for (int mf = 0; mf < 4; ++mf)
#pragma unroll
    for (int nf = 0; nf < 4; ++nf)
#pragma unroll
      for (int j = 0; j < 4; ++j) {
        int gm = m0 + (wm << 6) + (mf << 4) + (lhi << 2) + j;
        int gn = (wn << 6) + (nf << 4) + lrow;
        C[(size_t)gm * 256 + gn] = f2bf(acc[mf][nf][j]);
      }
}

// 8-edge batch load / consume helpers (statically unrolled; named buffers per rule #20)
#define LOAD8(V, W, EB)                                              \
  _Pragma("unroll")                                                  \
  for (int q = 0; q < 8; ++q) {                                      \
    uint32_t c = (uint32_t)RFL(ecol[(EB) + q]);                      \
    W[q] = __uint_as_float(RFL(__float_as_uint(ew[(EB) + q])));      \
    V[q] = *(const ushort4*)(Xb + ((c << 9) + c8));                  \
  }
#define CONS8(V, W)                                                  \
  _Pragma("unroll")                                                  \
  for (int q = 0; q < 8; ++q) {                                      \
    a0 += W[q] * b2f(V[q].x); a1 += W[q] * b2f(V[q].y);              \
    a2 += W[q] * b2f(V[q].z); a3 += W[q] * b2f(V[q].w);              \
  }

// ---- SpMM1 + bias + relu + dropout -> H (bf16). One wave per row, lane owns 4 cols.
// Scalarized edge stream + 2-stage software pipeline (16 gathers in flight).
__global__ __launch_bounds__(256) void spmm1_k(const unsigned short* __restrict__ XW1,
                                               const int* __restrict__ rowptr,
                                               const int* __restrict__ ecol,
                                               const float* __restrict__ ew,
                                               const float* __restrict__ b1,
                                               const float* __restrict__ du,
                                               unsigned short* __restrict__ H) {
  const int lane = threadIdx.x & 63, wid = threadIdx.x >> 6;
  const int r = blockIdx.x * 4 + wid;
  const uint32_t c8 = (uint32_t)lane << 3;  // lane's byte offset (4 bf16)
  const int c4 = lane << 2;
  if (r >= N_NODES) {  // pad rows: zero so GEMM2 reads clean zeros
    ushort4 z; z.x = z.y = z.z = z.w = 0;
    *(ushort4*)&H[(size_t)r * 256 + c4] = z;
    return;
  }
  const char* Xb = (const char*)XW1;
  const float4 bb = *(const float4*)&b1[c4];
  const f32x4_t u = __builtin_nontemporal_load((const f32x4_t*)&du[(size_t)r * 256 + c4]);
  float a0 = 0, a1 = 0, a2 = 0, a3 = 0;
  int e  = RFL(rowptr[r]);
  const int e1 = RFL(rowptr[r + 1]);
  ushort4 va[8], vb[8]; float wa[8], wb[8];
  if (e + 8 <= e1) {
    LOAD8(va, wa, e);
    for (; e + 24 <= e1; e += 16) {
      LOAD8(vb, wb, e + 8);
      CONS8(va, wa);
      LOAD8(va, wa, e + 16);
      CONS8(vb, wb);
    }
    if (e + 16 <= e1) {  // two batches left: va pending, fetch+consume vb
      LOAD8(vb, wb, e + 8);
      CONS8(va, wa);
      CONS8(vb, wb);
      e += 16;
    } else {
      CONS8(va, wa);
      e += 8;
    }
  }
  for (; e < e1; ++e) {
    uint32_t c = (uint32_t)RFL(ecol[e]);
    float w = __uint_as_float(RFL(__float_as_uint(ew[e])));
    ushort4 v = *(const ushort4*)(Xb + ((c << 9) + c8));
    a0 += w * b2f(v.x); a1 += w * b2f(v.y); a2 += w * b2f(v.z); a3 += w * b2f(v.w);
  }
  float h0 = fmaxf(a0 + bb.x, 0.f) * (u.x < 0.5f ? 2.f : 0.f);
  float h1 = fmaxf(a1 + bb.y, 0.f) * (u.y < 0.5f ? 2.f : 0.f);
  float h2 = fmaxf(a2 + bb.z, 0.f) * (u.z < 0.5f ? 2.f : 0.f);
  float h3 = fmaxf(a3 + bb.w, 0.f) * (u.w < 0.5f ? 2.f : 0.f);
  ushort4 o; o.x = f2bf(h0); o.y = f2bf(h1); o.z = f2bf(h2); o.w = f2bf(h3);
  *(ushort4*)&H[(size_t)r * 256 + c4] = o;  // cacheable: gemm2 reads it next
}

// ---- SpMM2 + bias + relu + log_softmax -> out (fp32)
__global__ __launch_bounds__(256) void spmm2_k(const unsigned short* __restrict__ HW2,
                                               const int* __restrict__ rowptr,
                                               const int* __restrict__ ecol,
                                               const float* __restrict__ ew,
                                               const float* __restrict__ b2,
                                               float* __restrict__ out) {
  const int lane = threadIdx.x & 63, wid = threadIdx.x >> 6;
  const int r = blockIdx.x * 4 + wid;
  if (r >= N_NODES) return;
  const uint32_t c8 = (uint32_t)lane << 3;
  const int c4 = lane << 2;
  const char* Xb = (const char*)HW2;
  const float4 bb = *(const float4*)&b2[c4];
  float a0 = 0, a1 = 0, a2 = 0, a3 = 0;
  int e  = RFL(rowptr[r]);
  const int e1 = RFL(rowptr[r + 1]);
  ushort4 va[8], vb[8]; float wa[8], wb[8];
  if (e + 8 <= e1) {
    LOAD8(va, wa, e);
    for (; e + 24 <= e1; e += 16) {
      LOAD8(vb, wb, e + 8);
      CONS8(va, wa);
      LOAD8(va, wa, e + 16);
      CONS8(vb, wb);
    }
    if (e + 16 <= e1) {
      LOAD8(vb, wb, e + 8);
      CONS8(va, wa);
      CONS8(vb, wb);
      e += 16;
    } else {
      CONS8(va, wa);
      e += 8;
    }
  }
  for (; e < e1; ++e) {
    uint32_t c = (uint32_t)RFL(ecol[e]);
    float w = __uint_as_float(RFL(__float_as_uint(ew[e])));
    ushort4 v = *(const ushort4*)(Xb + ((c << 9) + c8));
    a0 += w * b2f(v.x); a1 += w * b2f(v.y); a2 += w * b2f(v.z); a3 += w * b2f(v.w);
  }
  float v0 = fmaxf(a0 + bb.x, 0.f);
  float v1 = fmaxf(a1 + bb.y, 0.f);
  float v2 = fmaxf(a2 + bb.z, 0.f);
  float v3 = fmaxf(a3 + bb.w, 0.f);
  float m = fmaxf(fmaxf(v0, v1), fmaxf(v2, v3));
#pragma unroll
  for (int off = 32; off > 0; off >>= 1) m = fmaxf(m, __shfl_xor(m, off));
  float s = expf(v0 - m) + expf(v1 - m) + expf(v2 - m) + expf(v3 - m);
#pragma unroll
  for (int off = 32; off > 0; off >>= 1) s += __shfl_xor(s, off);
  float ls = m + logf(s);
  f32x4_t o; o.x = v0 - ls; o.y = v1 - ls; o.z = v2 - ls; o.w = v3 - ls;
  __builtin_nontemporal_store(o, (f32x4_t*)&out[(size_t)r * 256 + c4]);
}

extern "C" void kernel_launch(void* const* d_in, const int* in_sizes, int n_in,
                              void* d_out, int out_size, void* d_ws, size_t ws_size,
                              hipStream_t stream) {
  const float* x  = (const float*)d_in[0];
  const float* W1 = (const float*)d_in[1];
  const float* b1 = (const float*)d_in[2];
  const float* W2 = (const float*)d_in[3];
  const float* b2 = (const float*)d_in[4];
  const int* erow = (const int*)d_in[5];
  const int* ecol = (const int*)d_in[6];
  const float* ew = (const float*)d_in[7];
  const float* du = (const float*)d_in[8];
  float* out = (float*)d_out;

  char* ws = (char*)d_ws;
  unsigned short* W1T = (unsigned short*)ws;                    // 262144 B
  unsigned short* W2T = (unsigned short*)(ws + 262144);         // 131072 B
  int* rowptr = (int*)(ws + 262144 + 131072);                   // 400004 B (pad to 401408)
  unsigned short* XW1 = (unsigned short*)(ws + 262144 + 131072 + 401408);  // 51249152 B (reused as HW2)
  unsigned short* H = (unsigned short*)(ws + 262144 + 131072 + 401408 + 51249152);  // 51249152 B

  prep_k<<<768, 256, 0, stream>>>(W1, W2, W1T, W2T);
  rowptr_k<<<392, 256, 0, stream>>>(erow, rowptr);
  gemm_bt2<true><<<782, 512, 0, stream>>>((const void*)x, W1T, XW1, NFEAT, N_NODES);
  spmm1_k<<<MPAD / 4, 256, 0, stream>>>(XW1, rowptr, ecol, ew, b1, du, H);
  gemm_bt2<false><<<782, 512, 0, stream>>>((const void*)H, W2T, XW1, NHID, MPAD);
  spmm2_k<<<N_NODES / 4, 256, 0, stream>>>(XW1, rowptr, ecol, ew, b2, out);
}

// Round 4
// 547.646 us; speedup vs baseline: 1.1258x; 1.0045x over previous
//
#include <hip/hip_runtime.h>
#include <stdint.h>

#define N_NODES 100000
#define N_EDGES 3200000
#define NFEAT 512
#define NHID 256
#define MPAD 100096  // 782 * 128

typedef __attribute__((ext_vector_type(8))) short bf16x8_t;  // 8 bf16 in 4 VGPRs
typedef __attribute__((ext_vector_type(8))) unsigned short u16x8_t;
typedef __attribute__((ext_vector_type(4))) float f32x4_t;

#define RFL(x) __builtin_amdgcn_readfirstlane(x)

__device__ inline unsigned short f2bf(float f) {
  union { float f; uint32_t u; } x; x.f = f;
  uint32_t r = x.u + 0x7fffu + ((x.u >> 16) & 1u);  // RNE
  return (unsigned short)(r >> 16);
}
__device__ inline float b2f(unsigned short u) {
  union { uint32_t u; float f; } x; x.u = ((uint32_t)u) << 16;
  return x.f;
}

// ---- prep: W1 [512][256] -> W1T bf16 [256][512]; W2 [256][256] -> W2T bf16 [256][256]
__global__ void prep_k(const float* __restrict__ W1, const float* __restrict__ W2,
                       unsigned short* __restrict__ W1T, unsigned short* __restrict__ W2T) {
  int i = blockIdx.x * 256 + threadIdx.x;
  if (i < NFEAT * NHID) {
    int k = i >> 8, n = i & 255;
    W1T[n * NFEAT + k] = f2bf(W1[i]);
  } else {
    int j = i - NFEAT * NHID;
    int k = j >> 8, n = j & 255;
    W2T[n * NHID + k] = f2bf(W2[j]);
  }
}

// ---- row_ptr[r] = lower_bound(edge_row, r), r in [0, N_NODES]
__global__ void rowptr_k(const int* __restrict__ erow, int* __restrict__ rowptr) {
  int r = blockIdx.x * 256 + threadIdx.x;
  if (r > N_NODES) return;
  int lo = 0, hi = N_EDGES;
  while (lo < hi) {
    int mid = (lo + hi) >> 1;
    if (erow[mid] < r) lo = mid + 1; else hi = mid;
  }
  rowptr[r] = lo;
}

// ---- GEMM C[M][256] (bf16 out) = A[M][K] @ BT[256][K]^T
// BM=128, BN=256, BK=64, 512 threads (8 waves, 2x4), LDS 48KB, XOR-swizzled.
template <bool A_FP32>
__global__ __launch_bounds__(512) void gemm_bt2(const void* __restrict__ Ap,
                                                const unsigned short* __restrict__ BT,
                                                unsigned short* __restrict__ C,
                                                int K, int Mreal) {
  __shared__ __align__(16) unsigned short As[128 * 64];  // 16 KB
  __shared__ __align__(16) unsigned short Bs[256 * 64];  // 32 KB
  const int tid = threadIdx.x;
  const int lane = tid & 63, wid = tid >> 6;
  const int wm = wid >> 2, wn = wid & 3;  // 2 x 4 waves, each 64x64 out
  const int m0 = blockIdx.x * 128;
  const int lrow = lane & 15, lhi = lane >> 4;

  f32x4_t acc[4][4] = {};

  const int nt = K >> 6;
  for (int t = 0; t < nt; ++t) {
    __syncthreads();  // WAR
    if constexpr (A_FP32) {
      const float* A = (const float*)Ap;
      const int rr = tid >> 4;
      const int kq = (tid & 15) << 2;
#pragma unroll
      for (int round = 0; round < 4; ++round) {
        int row = rr + (round << 5);
        int grow = m0 + row; grow = grow < Mreal ? grow : Mreal - 1;
        const f32x4_t v = __builtin_nontemporal_load(
            (const f32x4_t*)(A + (size_t)grow * K + (t << 6) + kq));
        ushort4 b4;
        b4.x = f2bf(v.x); b4.y = f2bf(v.y); b4.z = f2bf(v.z); b4.w = f2bf(v.w);
        *(ushort4*)&As[(row << 6) + (kq ^ ((row & 7) << 3))] = b4;
      }
    } else {
      const unsigned short* A = (const unsigned short*)Ap;
      const int Lrow = tid >> 3;
      const int Lc = (tid & 7) << 4;
#pragma unroll
      for (int round = 0; round < 2; ++round) {
        int row = Lrow + (round << 6);
        int srcc = Lc ^ ((row & 7) << 4);
        const char* g = (const char*)(A + (size_t)(m0 + row) * K + (t << 6)) + srcc;
        __builtin_amdgcn_global_load_lds(
            (const __attribute__((address_space(1))) void*)g,
            (__attribute__((address_space(3))) void*)((char*)As + tid * 16 + (round << 13)),
            16, 0, 0);
      }
    }
    {
      const int Lrow = tid >> 3;
      const int Lc = (tid & 7) << 4;
#pragma unroll
      for (int round = 0; round < 4; ++round) {
        int row = Lrow + (round << 6);
        int srcc = Lc ^ ((row & 7) << 4);
        const char* g = (const char*)(BT + (size_t)row * K + (t << 6)) + srcc;
        __builtin_amdgcn_global_load_lds(
            (const __attribute__((address_space(1))) void*)g,
            (__attribute__((address_space(3))) void*)((char*)Bs + tid * 16 + (round << 13)),
            16, 0, 0);
      }
    }
    asm volatile("s_waitcnt vmcnt(0)" ::: "memory");
    __syncthreads();  // RAW

#pragma unroll
    for (int ks = 0; ks < 2; ++ks) {
      bf16x8_t af[4], bfr[4];
      const int cu = (ks << 5) + (lhi << 3);
#pragma unroll
      for (int mf = 0; mf < 4; ++mf) {
        int row = (wm << 6) + (mf << 4) + lrow;
        af[mf] = *(const bf16x8_t*)&As[(row << 6) + (cu ^ ((row & 7) << 3))];
      }
#pragma unroll
      for (int nf = 0; nf < 4; ++nf) {
        int row = (wn << 6) + (nf << 4) + lrow;
        bfr[nf] = *(const bf16x8_t*)&Bs[(row << 6) + (cu ^ ((row & 7) << 3))];
      }
#pragma unroll
      for (int mf = 0; mf < 4; ++mf)
#pragma unroll
        for (int nf = 0; nf < 4; ++nf)
          acc[mf][nf] = __builtin_amdgcn_mfma_f32_16x16x32_bf16(af[mf], bfr[nf], acc[mf][nf], 0, 0, 0);
    }
  }

#pragma unroll
  for (int mf = 0; mf < 4; ++mf)
#pragma unroll
    for (int nf = 0; nf < 4; ++nf)
#pragma unroll
      for (int j = 0; j < 4; ++j) {
        int gm = m0 + (wm << 6) + (mf << 4) + (lhi << 2) + j;
        int gn = (wn << 6) + (nf << 4) + lrow;
        C[(size_t)gm * 256 + gn] = f2bf(acc[mf][nf][j]);
      }
}

// Paired-edge batch helpers: 4 pairs (8 edges) per batch.
// lanes 0-31 take the even edge, 32-63 the odd edge; each lane owns 8 cols.
#define LOADP4(V, W, EB)                                             \
  _Pragma("unroll")                                                  \
  for (int q = 0; q < 4; ++q) {                                      \
    uint32_t ce = (uint32_t)RFL(ecol[(EB) + 2 * q]);                 \
    uint32_t co = (uint32_t)RFL(ecol[(EB) + 2 * q + 1]);             \
    uint32_t ue = RFL(__float_as_uint(ew[(EB) + 2 * q]));            \
    uint32_t uo = RFL(__float_as_uint(ew[(EB) + 2 * q + 1]));        \
    uint32_t cv = lo ? ce : co;                                      \
    W[q] = __uint_as_float(lo ? ue : uo);                            \
    V[q] = *(const u16x8_t*)(Xb + (((size_t)cv << 9) + c16));        \
  }
#define CONSP4(V, W)                                                 \
  _Pragma("unroll")                                                  \
  for (int q = 0; q < 4; ++q)                                        \
    _Pragma("unroll")                                                \
    for (int j = 0; j < 8; ++j)                                      \
      f[j] += W[q] * b2f(V[q][j]);

// Row-gather core shared by both spmms: accumulate f[8] per lane.
#define GATHER_ROW()                                                 \
  u16x8_t va[4], vb[4]; float wa[4], wb[4];                          \
  if (e + 8 <= e1) {                                                 \
    LOADP4(va, wa, e);                                               \
    for (; e + 24 <= e1; e += 16) {                                  \
      LOADP4(vb, wb, e + 8);                                         \
      CONSP4(va, wa);                                                \
      LOADP4(va, wa, e + 16);                                        \
      CONSP4(vb, wb);                                                \
    }                                                                \
    if (e + 16 <= e1) {                                              \
      LOADP4(vb, wb, e + 8);                                         \
      CONSP4(va, wa);                                                \
      CONSP4(vb, wb);                                                \
      e += 16;                                                       \
    } else { CONSP4(va, wa); e += 8; }                               \
  }                                                                  \
  for (; e < e1; ++e) {  /* remainder: half-wave predicated */       \
    uint32_t c = (uint32_t)RFL(ecol[e]);                             \
    float w = __uint_as_float(RFL(__float_as_uint(ew[e])));          \
    u16x8_t v = *(const u16x8_t*)(Xb + (((size_t)c << 9) + c16));    \
    float wv = lo ? w : 0.0f;                                        \
    _Pragma("unroll")                                                \
    for (int j = 0; j < 8; ++j) f[j] += wv * b2f(v[j]);              \
  }                                                                  \
  _Pragma("unroll")                                                  \
  for (int j = 0; j < 8; ++j) f[j] += __shfl_xor(f[j], 32);

// ---- SpMM1 + bias + relu + dropout -> H (bf16). One wave per row, paired-edge gather.
__global__ __launch_bounds__(256) void spmm1_k(const unsigned short* __restrict__ XW1,
                                               const int* __restrict__ rowptr,
                                               const int* __restrict__ ecol,
                                               const float* __restrict__ ew,
                                               const float* __restrict__ b1,
                                               const float* __restrict__ du,
                                               unsigned short* __restrict__ H) {
  const int lane = threadIdx.x & 63, wid = threadIdx.x >> 6;
  const int r = blockIdx.x * 4 + wid;
  const bool lo = lane < 32;
  const int g = lane & 31;
  const uint32_t c16 = (uint32_t)g << 4;  // byte offset: 8 bf16 per lane
  if (r >= N_NODES) {  // pad rows: zero so GEMM2 reads clean zeros
    if (lo) {
      u16x8_t z;
#pragma unroll
      for (int j = 0; j < 8; ++j) z[j] = 0;
      *(u16x8_t*)&H[(size_t)r * 256 + (g << 3)] = z;
    }
    return;
  }
  const char* Xb = (const char*)XW1;
  float f[8] = {};
  int e  = RFL(rowptr[r]);
  const int e1 = RFL(rowptr[r + 1]);
  GATHER_ROW();
  if (lo) {
    const int g8 = g << 3;
    float bv[8], uu[8];
    *(f32x4_t*)&bv[0] = *(const f32x4_t*)&b1[g8];
    *(f32x4_t*)&bv[4] = *(const f32x4_t*)&b1[g8 + 4];
    *(f32x4_t*)&uu[0] = __builtin_nontemporal_load((const f32x4_t*)&du[(size_t)r * 256 + g8]);
    *(f32x4_t*)&uu[4] = __builtin_nontemporal_load((const f32x4_t*)&du[(size_t)r * 256 + g8 + 4]);
    u16x8_t o;
#pragma unroll
    for (int j = 0; j < 8; ++j) {
      float h = fmaxf(f[j] + bv[j], 0.f) * (uu[j] < 0.5f ? 2.f : 0.f);
      o[j] = f2bf(h);
    }
    *(u16x8_t*)&H[(size_t)r * 256 + g8] = o;
  }
}

// ---- SpMM2 + bias + relu + log_softmax -> out (fp32)
__global__ __launch_bounds__(256) void spmm2_k(const unsigned short* __restrict__ HW2,
                                               const int* __restrict__ rowptr,
                                               const int* __restrict__ ecol,
                                               const float* __restrict__ ew,
                                               const float* __restrict__ b2,
                                               float* __restrict__ out) {
  const int lane = threadIdx.x & 63, wid = threadIdx.x >> 6;
  const int r = blockIdx.x * 4 + wid;
  if (r >= N_NODES) return;
  const bool lo = lane < 32;
  const int g = lane & 31;
  const uint32_t c16 = (uint32_t)g << 4;
  const char* Xb = (const char*)HW2;
  float f[8] = {};
  int e  = RFL(rowptr[r]);
  const int e1 = RFL(rowptr[r + 1]);
  GATHER_ROW();
  const int g8 = g << 3;
  float bv[8];
  *(f32x4_t*)&bv[0] = *(const f32x4_t*)&b2[g8];
  *(f32x4_t*)&bv[4] = *(const f32x4_t*)&b2[g8 + 4];
  float v[8];
#pragma unroll
  for (int j = 0; j < 8; ++j) v[j] = fmaxf(f[j] + bv[j], 0.f);
  float m = v[0];
#pragma unroll
  for (int j = 1; j < 8; ++j) m = fmaxf(m, v[j]);
#pragma unroll
  for (int off = 16; off > 0; off >>= 1) m = fmaxf(m, __shfl_xor(m, off));
  float s = 0.f;
#pragma unroll
  for (int j = 0; j < 8; ++j) s += expf(v[j] - m);
#pragma unroll
  for (int off = 16; off > 0; off >>= 1) s += __shfl_xor(s, off);
  const float ls = m + logf(s);
  if (lo) {
    f32x4_t o0, o1;
    o0.x = v[0] - ls; o0.y = v[1] - ls; o0.z = v[2] - ls; o0.w = v[3] - ls;
    o1.x = v[4] - ls; o1.y = v[5] - ls; o1.z = v[6] - ls; o1.w = v[7] - ls;
    __builtin_nontemporal_store(o0, (f32x4_t*)&out[(size_t)r * 256 + g8]);
    __builtin_nontemporal_store(o1, (f32x4_t*)&out[(size_t)r * 256 + g8 + 4]);
  }
}

extern "C" void kernel_launch(void* const* d_in, const int* in_sizes, int n_in,
                              void* d_out, int out_size, void* d_ws, size_t ws_size,
                              hipStream_t stream) {
  const float* x  = (const float*)d_in[0];
  const float* W1 = (const float*)d_in[1];
  const float* b1 = (const float*)d_in[2];
  const float* W2 = (const float*)d_in[3];
  const float* b2 = (const float*)d_in[4];
  const int* erow = (const int*)d_in[5];
  const int* ecol = (const int*)d_in[6];
  const float* ew = (const float*)d_in[7];
  const float* du = (const float*)d_in[8];
  float* out = (float*)d_out;

  char* ws = (char*)d_ws;
  unsigned short* W1T = (unsigned short*)ws;                    // 262144 B
  unsigned short* W2T = (unsigned short*)(ws + 262144);         // 131072 B
  int* rowptr = (int*)(ws + 262144 + 131072);                   // 400004 B (pad to 401408)
  unsigned short* XW1 = (unsigned short*)(ws + 262144 + 131072 + 401408);  // 51249152 B (reused as HW2)
  unsigned short* H = (unsigned short*)(ws + 262144 + 131072 + 401408 + 51249152);  // 51249152 B

  prep_k<<<768, 256, 0, stream>>>(W1, W2, W1T, W2T);
  rowptr_k<<<392, 256, 0, stream>>>(erow, rowptr);
  gemm_bt2<true><<<782, 512, 0, stream>>>((const void*)x, W1T, XW1, NFEAT, N_NODES);
  spmm1_k<<<MPAD / 4, 256, 0, stream>>>(XW1, rowptr, ecol, ew, b1, du, H);
  gemm_bt2<false><<<782, 512, 0, stream>>>((const void*)H, W2T, XW1, NHID, MPAD);
  spmm2_k<<<N_NODES / 4, 256, 0, stream>>>(XW1, rowptr, ecol, ew, b2, out);
}